// Round 10
// baseline (172.972 us; speedup 1.0000x reference)
//
#include <hip/hip_runtime.h>
#include <hip/hip_cooperative_groups.h>
#include <stdint.h>
#include <stddef.h>

namespace cg = cooperative_groups;

// Problem constants
#define NB   16
#define NC   64
#define NH   64
#define NW   64
#define KC   16
#define NOUT 64
#define NRANK 8
#define NMLP 32
#define NF   576      // C*3*3
#define NPIX 4096     // H*W
#define XH   66       // halo height/width for channel-last copy
#define SMEMB 37888   // shared scratch per block (4 blocks/CU: 4x37888 <= 160 KiB)

typedef short s16x8 __attribute__((ext_vector_type(8)));
typedef short s16x4 __attribute__((ext_vector_type(4)));
typedef float f32x4 __attribute__((ext_vector_type(4)));

__device__ __forceinline__ unsigned short f2bf(float x) {
    union { float f; uint32_t u; } v; v.f = x;
    uint32_t r = v.u + 0x7FFFu + ((v.u >> 16) & 1u);   // RTNE
    return (unsigned short)(r >> 16);
}
__device__ __forceinline__ float bf2f(unsigned short u) {
    union { uint32_t u; float f; } v; v.u = ((uint32_t)u) << 16;
    return v.f;
}

// ===========================================================================
// Phase device functions. All are deterministic; the cooperative kernel and
// the fallback per-phase kernels share them bit-for-bit (tripwire safety).
// Register discipline (R7 lesson): every local array fully unrolled.
// ===========================================================================

// ---- P0: prep. units 0..1055: xcl rows (b = u&15, yy = u>>4). units
// 1056..1127: basekF (ks*4+wv). grid 1024: block u and u+1024.
__device__ void phase_prep(int blk, int tid, const float* __restrict__ x,
                           const float* __restrict__ basek,
                           unsigned short* __restrict__ xcl,
                           unsigned short* __restrict__ basekF,
                           unsigned char* smem)
{
    float* tile = (float*)smem;                      // 64*65*4 = 16640 B
    for (int u = blk; u < 1128; u += 1024) {
        if (u < 1056) {
            const int b = u & 15, yy = u >> 4;
            unsigned short* dst = xcl + ((size_t)(b * XH + yy) * XH) * 64;
            if (yy == 0 || yy == XH - 1) {
                for (int e = tid; e < XH * 64; e += 256) dst[e] = 0;
            } else {
                const int y = yy - 1;
                const float* src = x + (size_t)b * NC * (NH * NW) + y * NW;
                #pragma unroll
                for (int rr = 0; rr < 16; ++rr) {
                    int c = rr * 4 + (tid >> 6);
                    int xx = tid & 63;
                    tile[c * 65 + xx] = src[(size_t)c * (NH * NW) + xx];
                }
                __syncthreads();
                for (int ee = tid; ee < 528; ee += 256) {
                    int xx = ee >> 3;
                    int c0 = (ee & 7) * 8;
                    s16x8 v;
                    #pragma unroll
                    for (int j = 0; j < 8; ++j) {
                        float f = (xx == 0 || xx == XH - 1) ? 0.f
                                : tile[(c0 + j) * 65 + (xx - 1)];
                        v[j] = (short)f2bf(f);
                    }
                    *reinterpret_cast<s16x8*>(dst + ee * 8) = v;
                }
                __syncthreads();
            }
        } else {
            const int bb = u - 1056;                 // ks*4 + wv
            const int ks = bb >> 2, wv = bb & 3;
            unsigned short outv[16];
            #pragma unroll
            for (int i = 0; i < 16; ++i) {
                int e = tid * 16 + i;                // e = r*512 + lane*8 + j
                int r = e >> 9;
                int ln = (e >> 3) & 63;
                int j = e & 7;
                int col = wv * 16 + (ln & 15);
                int fp = (ln >> 4) * 8 + ks * 32 + j;
                int tap = fp >> 6, c = fp & 63;
                outv[i] = f2bf(basek[((size_t)r * NF + c * 9 + tap) * NOUT + col]);
            }
            unsigned short* dst = basekF + (size_t)bb * 4096 + tid * 16;
            #pragma unroll
            for (int i = 0; i < 16; ++i) dst[i] = outv[i];
        }
    }
}

// ---- P1a: per-(b,k) order-preserving compaction (all 4 sibling blocks build
// identical lists), j==0 writes canonical lists/slotmap/counts. Tap-split
// gather: block j handles taps {j, j+4, (8 if j==0)}; 16 pixel-groups/tap.
// Writes centers2[bk][tap*64+c] (coalesced).
__device__ void phase_centers(int blk, int tid,
                              const unsigned short* __restrict__ xcl,
                              const int* __restrict__ labels,
                              unsigned short* __restrict__ lists,
                              unsigned short* __restrict__ slotmap,
                              int* __restrict__ counts,
                              float* __restrict__ centers2,
                              unsigned char* smem)
{
    const int bk = blk & 255, j = blk >> 8;
    const int b = bk & 15, k = bk >> 4;
    const int lane = tid & 63, wv = tid >> 6;
    unsigned short* list = (unsigned short*)smem;    // 8192 B
    int* wcnt4 = (int*)(smem + 8192);                // 16 B
    float* wsum = (float*)(smem + 8208);             // 1024 B
    const int* lab = labels + b * NPIX;

    int total = 0;
    for (int base = 0; base < NPIX; base += 256) {
        int n = base + tid;
        bool pred = (lab[n] == k);
        unsigned long long m = __ballot(pred);
        if (lane == 0) wcnt4[wv] = __popcll(m);
        int pre = __popcll(m & ((1ull << lane) - 1ull));
        __syncthreads();
        int wbase = total;
        for (int i = 0; i < wv; ++i) wbase += wcnt4[i];
        int nt = total;
        for (int i = 0; i < 4; ++i) nt += wcnt4[i];
        if (pred) {
            int slot = wbase + pre;
            list[slot] = (unsigned short)n;
            if (j == 0) slotmap[b * NPIX + n] = (unsigned short)slot;
        }
        total = nt;
        __syncthreads();
    }
    const int cnt = total;
    if (j == 0) {
        for (int i = tid; i < cnt; i += 256) lists[bk * NPIX + i] = list[i];
        if (tid == 0) counts[bk] = cnt;
    }

    const int pg = (wv << 2) + (lane >> 4);          // 0..15
    const int cq = lane & 15;
    const unsigned short* xb = xcl + (size_t)b * (XH * XH * 64);
    const float inv = 1.f / ((float)cnt + 1e-6f);
    #pragma unroll 1
    for (int tt = 0; tt < 3; ++tt) {
        int tap = j + tt * 4;
        if (tap > 8) break;                          // j>0: 2 taps; j==0: 3
        int dy = tap / 3, dx = tap - dy * 3;
        float s0 = 0.f, s1 = 0.f, s2 = 0.f, s3 = 0.f;
        #pragma unroll 2
        for (int i = pg; i < cnt; i += 16) {
            int n = list[i];
            const unsigned short* pr =
                xb + ((((n >> 6) + dy) * XH) + (n & 63) + dx) * 64 + cq * 4;
            s16x4 vv = *reinterpret_cast<const s16x4*>(pr);
            s0 += bf2f((unsigned short)vv[0]);
            s1 += bf2f((unsigned short)vv[1]);
            s2 += bf2f((unsigned short)vv[2]);
            s3 += bf2f((unsigned short)vv[3]);
        }
        s0 += __shfl_xor(s0, 16); s0 += __shfl_xor(s0, 32);
        s1 += __shfl_xor(s1, 16); s1 += __shfl_xor(s1, 32);
        s2 += __shfl_xor(s2, 16); s2 += __shfl_xor(s2, 32);
        s3 += __shfl_xor(s3, 16); s3 += __shfl_xor(s3, 32);
        if ((lane >> 4) == 0) {
            wsum[wv * 64 + cq * 4 + 0] = s0;
            wsum[wv * 64 + cq * 4 + 1] = s1;
            wsum[wv * 64 + cq * 4 + 2] = s2;
            wsum[wv * 64 + cq * 4 + 3] = s3;
        }
        __syncthreads();
        if (tid < 64) {
            float s = wsum[tid] + wsum[64 + tid] + wsum[128 + tid] + wsum[192 + tid];
            centers2[(size_t)bk * NF + tap * 64 + tid] = s * inv;
        }
        __syncthreads();
    }
}

// ---- P1b: MLPs (blocks 0..255 only; bk = blk). centers2 -> lr, biasrows.
__device__ void phase_mlp(int blk, int tid, const float* __restrict__ centers2,
                          const float* __restrict__ lw1, const float* __restrict__ lb1,
                          const float* __restrict__ lw2, const float* __restrict__ lb2,
                          const float* __restrict__ lw3, const float* __restrict__ lb3,
                          const float* __restrict__ bw1, const float* __restrict__ bb1,
                          const float* __restrict__ bw2, const float* __restrict__ bb2,
                          float* __restrict__ lrout, float* __restrict__ biasrows,
                          unsigned char* smem)
{
    const int bk = blk;
    float* cbuf = (float*)smem;                      // 576
    float* p1 = cbuf + 576;                          // 256
    float* pb = p1 + 256;                            // 256
    float* h1 = pb + 256;                            // 32
    float* h2 = h1 + 32;                             // 32
    float* hb = h2 + 32;                             // 32
    for (int i = tid; i < NF; i += 256) {
        int tap = i >> 6, c = i & 63;
        cbuf[c * 9 + tap] = centers2[(size_t)bk * NF + i];
    }
    __syncthreads();
    {
        const int jj = tid & 31, ch = tid >> 5;      // 8 chunks x 72 feats
        float a1 = 0.f, a2 = 0.f;
        for (int i = 0; i < 72; ++i) {
            int f = ch * 72 + i;
            float cv = cbuf[f];
            a1 += cv * lw1[f * NMLP + jj];
            a2 += cv * bw1[f * NMLP + jj];
        }
        p1[ch * 32 + jj] = a1; pb[ch * 32 + jj] = a2;
    }
    __syncthreads();
    if (tid < NMLP) {
        float a = lb1[tid];
        for (int i = 0; i < 8; ++i) a += p1[i * 32 + tid];
        h1[tid] = fmaxf(a, 0.f);
    } else if (tid < 2 * NMLP) {
        int jj = tid - NMLP;
        float a = bb1[jj];
        for (int i = 0; i < 8; ++i) a += pb[i * 32 + jj];
        hb[jj] = fmaxf(a, 0.f);
    }
    __syncthreads();
    if (tid < NMLP) {
        float a = lb2[tid];
        for (int i = 0; i < NMLP; ++i) a += h1[i] * lw2[i * NMLP + tid];
        h2[tid] = fmaxf(a, 0.f);
    } else if (tid >= 64 && tid < 128) {
        int o = tid - 64;
        float a = bb2[o];
        for (int i = 0; i < NMLP; ++i) a += hb[i] * bw2[i * NOUT + o];
        biasrows[bk * NOUT + o] = a;
    }
    __syncthreads();
    if (tid < NRANK) {
        float a = lb3[tid];
        for (int i = 0; i < NMLP; ++i) a += h2[i] * lw3[i * NRANK + tid];
        lrout[bk * NRANK + tid] = a;
    }
}

// ---- P1c: W-expansion. block (bk, j): ks range {0-4,5-9,10-13,14-17}.
// wt[bk][ks][t][8] = sum_r lr[r]*basekF[...] (coalesced in and out).
__device__ void phase_wexp(int blk, int tid, const unsigned short* __restrict__ basekF,
                           const float* __restrict__ lr, unsigned short* __restrict__ wt)
{
    const int bk = blk & 255, j = blk >> 8;
    const int start = (j < 2) ? j * 5 : 10 + (j - 2) * 4;
    const int end   = start + ((j < 2) ? 5 : 4);
    float l8[NRANK];
    #pragma unroll
    for (int r = 0; r < NRANK; ++r) l8[r] = lr[bk * NRANK + r];
    unsigned short* wtg = wt + (size_t)bk * (18 * 2048);
    #pragma unroll 1
    for (int ks = start; ks < end; ++ks) {
        const unsigned short* src = basekF
            + ((size_t)(ks * 4 + (tid >> 6)) * 8) * 512 + (tid & 63) * 8;
        float w[8] = {0.f, 0.f, 0.f, 0.f, 0.f, 0.f, 0.f, 0.f};
        #pragma unroll
        for (int r = 0; r < NRANK; ++r) {
            s16x8 bv = *reinterpret_cast<const s16x8*>(src + r * 512);
            #pragma unroll
            for (int q = 0; q < 8; ++q)
                w[q] += l8[r] * bf2f((unsigned short)bv[q]);
        }
        s16x8 f;
        #pragma unroll
        for (int q = 0; q < 8; ++q) f[q] = (short)f2bf(w[q]);
        *reinterpret_cast<s16x8*>(wtg + ks * 2048 + tid * 8) = f;
    }
}

// ---- P2: gathered GEMM (R9 k_main body). block (bk, split).
__device__ void phase_gemm(int blk, int tid, const unsigned short* __restrict__ xcl,
                           const unsigned short* __restrict__ lists,
                           const int* __restrict__ counts,
                           const unsigned short* __restrict__ wt,
                           const float* __restrict__ biasrows,
                           unsigned short* __restrict__ outc, unsigned char* smem)
{
    const int bk = blk & 255, split = blk >> 8;
    const int b = bk & 15, k = bk >> 4;
    const int lane = tid & 63, wv = tid >> 6;
    const int quad = lane >> 4, l16 = lane & 15;
    const int cnt = counts[bk];
    int prefix = 0;
    for (int kk = 0; kk < k; ++kk) prefix += counts[kk * 16 + b];

    unsigned short* albuf = (unsigned short*)smem;   // 32*584*2 = 37376 B
    float* biasl = (float*)(smem + 37376);           // 256 B

    if (tid < NOUT) biasl[tid] = biasrows[bk * NOUT + tid];

    const int col = wv * 16 + l16;
    const unsigned short* wsrc = wt + (size_t)bk * (18 * 2048) + tid * 8;
    s16x8 bfr[18];
    #pragma unroll
    for (int ks = 0; ks < 18; ++ks)
        bfr[ks] = *reinterpret_cast<const s16x8*>(wsrc + ks * 2048);

    const unsigned short* xb = xcl + (size_t)b * (XH * XH * 64);
    const unsigned short* gl = lists + bk * NPIX;
    const int p = tid >> 3, part = tid & 7;
    const int ntile = (cnt + 31) >> 5;

    for (int t = split; t < ntile; t += 4) {
        int slot = (t << 5) + p;
        int n = (slot < cnt) ? (int)gl[slot] : 0;
        const unsigned short* xrow = xb + (((n >> 6) * XH) + (n & 63)) * 64 + part * 8;
        unsigned short* arow = albuf + p * 584 + part * 8;
        #pragma unroll
        for (int tap = 0; tap < 9; ++tap) {
            int dy = tap / 3, dx = tap - dy * 3;
            *reinterpret_cast<s16x8*>(arow + tap * 64) =
                *reinterpret_cast<const s16x8*>(xrow + (dy * XH + dx) * 64);
        }
        __syncthreads();

        f32x4 acc0 = {0.f, 0.f, 0.f, 0.f}, acc1 = {0.f, 0.f, 0.f, 0.f};
        const unsigned short* ar0 = albuf + l16 * 584 + quad * 8;
        const unsigned short* ar1 = ar0 + 16 * 584;
        #pragma unroll
        for (int ks = 0; ks < 18; ++ks) {
            s16x8 a0 = *reinterpret_cast<const s16x8*>(ar0 + ks * 32);
            s16x8 a1 = *reinterpret_cast<const s16x8*>(ar1 + ks * 32);
            acc0 = __builtin_amdgcn_mfma_f32_16x16x32_bf16(a0, bfr[ks], acc0, 0, 0, 0);
            acc1 = __builtin_amdgcn_mfma_f32_16x16x32_bf16(a1, bfr[ks], acc1, 0, 0, 0);
        }
        __syncthreads();

        float bb = biasl[col];
        unsigned short* ob = outc + ((size_t)b * NPIX + prefix) * 64;
        #pragma unroll
        for (int r = 0; r < 4; ++r) {
            int s0 = (t << 5) + quad * 4 + r;
            if (s0 < cnt) ob[(size_t)s0 * 64 + col] = f2bf(acc0[r] + bb);
            int s1 = s0 + 16;
            if (s1 < cnt) ob[(size_t)s1 * 64 + col] = f2bf(acc1[r] + bb);
        }
    }
}

// ---- P3: scatter. block (b, chunk, q): o-range [q*16, q*16+16).
// outc rows gathered 32B/lane, LDS transpose (rows padded to 20 u16),
// coalesced f32 stores.
__device__ void phase_scatter(int blk, int tid, const int* __restrict__ labels,
                              const unsigned short* __restrict__ slotmap,
                              const int* __restrict__ counts,
                              const unsigned short* __restrict__ outc,
                              float* __restrict__ out, unsigned char* smem)
{
    const int b = blk & 15, chunk = (blk >> 4) & 15, q = blk >> 8;
    int* pref = (int*)smem;                          // 64 B
    int* sptr = (int*)(smem + 64);                   // 1024 B
    unsigned short* tt = (unsigned short*)(smem + 1088);  // 256*20*2 = 10240 B
    if (tid < KC) {
        int s = 0;
        for (int kk = 0; kk < tid; ++kk) s += counts[kk * 16 + b];
        pref[tid] = s;
    }
    __syncthreads();
    const int n0 = chunk * 256;
    {
        int n = n0 + tid;
        sptr[tid] = pref[labels[b * NPIX + n]] + (int)slotmap[b * NPIX + n];
    }
    __syncthreads();
    #pragma unroll
    for (int e0 = 0; e0 < 2; ++e0) {
        int e = e0 * 256 + tid;
        int pix = e >> 1, part = e & 1;
        s16x8 vv = *reinterpret_cast<const s16x8*>(
            outc + ((size_t)b * NPIX + sptr[pix]) * 64 + q * 16 + part * 8);
        s16x4 lo = {vv[0], vv[1], vv[2], vv[3]};
        s16x4 hi = {vv[4], vv[5], vv[6], vv[7]};
        *reinterpret_cast<s16x4*>(tt + pix * 20 + part * 8) = lo;
        *reinterpret_cast<s16x4*>(tt + pix * 20 + part * 8 + 4) = hi;
    }
    __syncthreads();
    float* ob = out + ((size_t)(b * NOUT + q * 16)) * NPIX + n0;
    #pragma unroll
    for (int oo = 0; oo < 16; ++oo)
        ob[(size_t)oo * NPIX + tid] = bf2f(tt[tid * 20 + oo]);
}

// ===========================================================================
// Cooperative mega-kernel: all phases + grid.sync. grid 1024 x 256.
// ===========================================================================
extern "C" __global__ __launch_bounds__(256, 4)
void k_fused(const float* x, const int* labels,
             const float* lw1, const float* lb1, const float* lw2, const float* lb2,
             const float* lw3, const float* lb3, const float* basek,
             const float* bw1, const float* bb1, const float* bw2, const float* bb2,
             float* out,
             unsigned short* lists, unsigned short* slotmap, int* counts,
             float* centers2, float* lr, float* biasrows,
             unsigned short* basekF, unsigned short* xcl, unsigned short* wt,
             unsigned short* outc)
{
    __shared__ __align__(16) unsigned char smem[SMEMB];
    cg::grid_group grid = cg::this_grid();
    const int blk = blockIdx.x, tid = threadIdx.x;

    phase_prep(blk, tid, x, basek, xcl, basekF, smem);
    grid.sync();
    phase_centers(blk, tid, xcl, labels, lists, slotmap, counts, centers2, smem);
    grid.sync();
    if (blk < 256)
        phase_mlp(blk, tid, centers2, lw1, lb1, lw2, lb2, lw3, lb3,
                  bw1, bb1, bw2, bb2, lr, biasrows, smem);
    grid.sync();
    phase_wexp(blk, tid, basekF, lr, wt);
    grid.sync();
    phase_gemm(blk, tid, xcl, lists, counts, wt, biasrows, outc, smem);
    grid.sync();
    phase_scatter(blk, tid, labels, slotmap, counts, outc, out, smem);
}

// ===========================================================================
// Fallback: same phases as separate kernels (identical numerics).
// ===========================================================================
extern "C" __global__ __launch_bounds__(256, 4)
void k_p0(const float* x, const float* basek, unsigned short* xcl, unsigned short* basekF)
{ __shared__ __align__(16) unsigned char smem[SMEMB];
  phase_prep(blockIdx.x, threadIdx.x, x, basek, xcl, basekF, smem); }

extern "C" __global__ __launch_bounds__(256, 4)
void k_p1(const unsigned short* xcl, const int* labels, unsigned short* lists,
          unsigned short* slotmap, int* counts, float* centers2)
{ __shared__ __align__(16) unsigned char smem[SMEMB];
  phase_centers(blockIdx.x, threadIdx.x, xcl, labels, lists, slotmap, counts, centers2, smem); }

extern "C" __global__ __launch_bounds__(256, 4)
void k_p2(const float* centers2, const float* lw1, const float* lb1,
          const float* lw2, const float* lb2, const float* lw3, const float* lb3,
          const float* bw1, const float* bb1, const float* bw2, const float* bb2,
          float* lr, float* biasrows)
{ __shared__ __align__(16) unsigned char smem[SMEMB];
  phase_mlp(blockIdx.x, threadIdx.x, centers2, lw1, lb1, lw2, lb2, lw3, lb3,
            bw1, bb1, bw2, bb2, lr, biasrows, smem); }

extern "C" __global__ __launch_bounds__(256, 4)
void k_p3(const unsigned short* basekF, const float* lr, unsigned short* wt)
{ phase_wexp(blockIdx.x, threadIdx.x, basekF, lr, wt); }

extern "C" __global__ __launch_bounds__(256, 4)
void k_p4(const unsigned short* xcl, const unsigned short* lists, const int* counts,
          const unsigned short* wt, const float* biasrows, unsigned short* outc)
{ __shared__ __align__(16) unsigned char smem[SMEMB];
  phase_gemm(blockIdx.x, threadIdx.x, xcl, lists, counts, wt, biasrows, outc, smem); }

extern "C" __global__ __launch_bounds__(256, 4)
void k_p5(const int* labels, const unsigned short* slotmap, const int* counts,
          const unsigned short* outc, float* out)
{ __shared__ __align__(16) unsigned char smem[SMEMB];
  phase_scatter(blockIdx.x, threadIdx.x, labels, slotmap, counts, outc, out, smem); }

// ---------------------------------------------------------------------------
// Workspace layout — TOTAL 39,666,688 B (ws ~256 MiB per R8 profile):
//   lists    @ 0         : 2,097,152
//   counts   @ 2097152   : 1,024
//   biasrows @ 2098176   : 65,536
//   lr       @ 2163712   : 8,192
//   centers2 @ 2171904   : 589,824
//   basekF   @ 2761728   : 589,824
//   slotmap  @ 3351552   : 131,072
//   xcl      @ 3482624   : 8,921,088
//   outc     @ 12403712  : 8,388,608
//   wt       @ 20792320  : 18,874,368
// ---------------------------------------------------------------------------
extern "C" void kernel_launch(void* const* d_in, const int* in_sizes, int n_in,
                              void* d_out, int out_size, void* d_ws, size_t ws_size,
                              hipStream_t stream)
{
    const float* x      = (const float*)d_in[0];
    const int*   labels = (const int*)d_in[1];
    const float* lw1    = (const float*)d_in[2];
    const float* lb1    = (const float*)d_in[3];
    const float* lw2    = (const float*)d_in[4];
    const float* lb2    = (const float*)d_in[5];
    const float* lw3    = (const float*)d_in[6];
    const float* lb3    = (const float*)d_in[7];
    const float* basek  = (const float*)d_in[8];
    const float* bw1    = (const float*)d_in[9];
    const float* bb1    = (const float*)d_in[10];
    const float* bw2    = (const float*)d_in[11];
    const float* bb2    = (const float*)d_in[12];
    float* out = (float*)d_out;

    char* ws = (char*)d_ws;
    unsigned short* lists   = (unsigned short*)(ws);
    int*            counts  = (int*)(ws + 2097152);
    float*          biasrows= (float*)(ws + 2098176);
    float*          lr      = (float*)(ws + 2163712);
    float*          centers2= (float*)(ws + 2171904);
    unsigned short* basekF  = (unsigned short*)(ws + 2761728);
    unsigned short* slotmap = (unsigned short*)(ws + 3351552);
    unsigned short* xcl     = (unsigned short*)(ws + 3482624);
    unsigned short* outc    = (unsigned short*)(ws + 12403712);
    unsigned short* wt      = (unsigned short*)(ws + 20792320);

    // Deterministic pre-check: cooperative grid 1024 needs 4 blocks/CU.
    int nb = 0;
    hipError_t occ = hipOccupancyMaxActiveBlocksPerMultiprocessor(&nb, k_fused, 256, 0);
    bool try_coop = (occ == hipSuccess) && (nb >= 4);

    hipError_t err = hipErrorUnknown;
    if (try_coop) {
        void* kargs[] = {
            (void*)&x, (void*)&labels,
            (void*)&lw1, (void*)&lb1, (void*)&lw2, (void*)&lb2,
            (void*)&lw3, (void*)&lb3, (void*)&basek,
            (void*)&bw1, (void*)&bb1, (void*)&bw2, (void*)&bb2,
            (void*)&out,
            (void*)&lists, (void*)&slotmap, (void*)&counts,
            (void*)&centers2, (void*)&lr, (void*)&biasrows,
            (void*)&basekF, (void*)&xcl, (void*)&wt, (void*)&outc };
        err = hipLaunchCooperativeKernel((const void*)k_fused, dim3(1024), dim3(256),
                                         kargs, 0, stream);
    }
    if (err != hipSuccess) {
        // Fallback: identical phases, 6 plain launches.
        k_p0<<<1024, 256, 0, stream>>>(x, basek, xcl, basekF);
        k_p1<<<1024, 256, 0, stream>>>(xcl, labels, lists, slotmap, counts, centers2);
        k_p2<<<256, 256, 0, stream>>>(centers2, lw1, lb1, lw2, lb2, lw3, lb3,
                                      bw1, bb1, bw2, bb2, lr, biasrows);
        k_p3<<<1024, 256, 0, stream>>>(basekF, lr, wt);
        k_p4<<<1024, 256, 0, stream>>>(xcl, lists, counts, wt, biasrows, outc);
        k_p5<<<1024, 256, 0, stream>>>(labels, slotmap, counts, outc, out);
    }
}

// Round 11
// 139.503 us; speedup vs baseline: 1.2399x; 1.2399x over previous
//
#include <hip/hip_runtime.h>
#include <stdint.h>
#include <stddef.h>

// Problem constants
#define NB   16
#define NC   64
#define NH   64
#define NW   64
#define KC   16
#define NOUT 64
#define NRANK 8
#define NMLP 32
#define NF   576      // C*3*3
#define NPIX 4096     // H*W
#define XH   66       // halo height/width for channel-last copy

typedef short s16x8 __attribute__((ext_vector_type(8)));
typedef short s16x4 __attribute__((ext_vector_type(4)));
typedef float f32x4 __attribute__((ext_vector_type(4)));

__device__ __forceinline__ unsigned short f2bf(float x) {
    union { float f; uint32_t u; } v; v.f = x;
    uint32_t r = v.u + 0x7FFFu + ((v.u >> 16) & 1u);   // RTNE
    return (unsigned short)(r >> 16);
}
__device__ __forceinline__ float bf2f(unsigned short u) {
    union { uint32_t u; float f; } v; v.u = ((uint32_t)u) << 16;
    return v.f;
}

// ---------------------------------------------------------------------------
// k_prep_all (R9, unchanged): blocks [0,1056): xcl; [1056,1128): basekF.
// ---------------------------------------------------------------------------
extern "C" __global__ __launch_bounds__(256)
void k_prep_all(const float* __restrict__ x, const float* __restrict__ basek,
                unsigned short* __restrict__ xcl, unsigned short* __restrict__ basekF)
{
    __shared__ float tile[64 * 65];
    const int blk0 = blockIdx.x;
    const int tid = threadIdx.x;
    if (blk0 < XH * 16) {
        const int b = blk0 & 15, yy = blk0 >> 4;
        unsigned short* dst = xcl + ((size_t)(b * XH + yy) * XH) * 64;
        if (yy == 0 || yy == XH - 1) {
            for (int e = tid; e < XH * 64; e += 256) dst[e] = 0;
            return;
        }
        const int y = yy - 1;
        const float* src = x + (size_t)b * NC * (NH * NW) + y * NW;
        #pragma unroll
        for (int rr = 0; rr < 16; ++rr) {
            int c = rr * 4 + (tid >> 6);
            int xx = tid & 63;
            tile[c * 65 + xx] = src[(size_t)c * (NH * NW) + xx];
        }
        __syncthreads();
        for (int ee = tid; ee < 528; ee += 256) {
            int xx = ee >> 3;
            int c0 = (ee & 7) * 8;
            s16x8 v;
            #pragma unroll
            for (int j = 0; j < 8; ++j) {
                float f = (xx == 0 || xx == XH - 1) ? 0.f : tile[(c0 + j) * 65 + (xx - 1)];
                v[j] = (short)f2bf(f);
            }
            *reinterpret_cast<s16x8*>(dst + ee * 8) = v;
        }
    } else {
        const int blk = blk0 - XH * 16;    // ks*4 + wv
        const int ks = blk >> 2, wv = blk & 3;
        unsigned short outv[16];
        #pragma unroll
        for (int i = 0; i < 16; ++i) {
            int e = tid * 16 + i;          // e = r*512 + lane*8 + j
            int r = e >> 9;
            int lane = (e >> 3) & 63;
            int j = e & 7;
            int col = wv * 16 + (lane & 15);
            int fp = (lane >> 4) * 8 + ks * 32 + j;
            int tap = fp >> 6, c = fp & 63;
            outv[i] = f2bf(basek[((size_t)r * NF + c * 9 + tap) * NOUT + col]);
        }
        unsigned short* dst = basekF + (size_t)blk * 4096 + tid * 16;
        #pragma unroll
        for (int i = 0; i < 16; ++i) dst[i] = outv[i];
    }
}

// ---------------------------------------------------------------------------
// k_centers: 1024 threads (16 waves/CU) — R11 TLP fix for the 1-block/CU
// latency-bound gather. Phases: compaction (4 ballot iters) -> gather
// (wave = pixel-slice, lane = channel, 9 independent tap loads per step) ->
// 16-wave LDS reduction -> MLPs -> W-expansion into wt (k_main order).
// grid 256 (k*16+b).
// ---------------------------------------------------------------------------
extern "C" __global__ __launch_bounds__(1024)
void k_centers(const unsigned short* __restrict__ xcl, const int* __restrict__ labels,
               const float* __restrict__ lw1, const float* __restrict__ lb1,
               const float* __restrict__ lw2, const float* __restrict__ lb2,
               const float* __restrict__ lw3, const float* __restrict__ lb3,
               const float* __restrict__ bw1, const float* __restrict__ bb1,
               const float* __restrict__ bw2, const float* __restrict__ bb2,
               const unsigned short* __restrict__ basekF,
               unsigned short* __restrict__ lists, unsigned short* __restrict__ slotmap,
               int* __restrict__ counts, float* __restrict__ biasrows,
               unsigned short* __restrict__ wt)
{
    const int bk = blockIdx.x;
    const int b = bk & 15, k = bk >> 4;
    __shared__ unsigned short list[NPIX];        // 8 KB
    __shared__ int wcnt[16];
    __shared__ float wsum[16 * 9 * 64];          // 36.9 KB
    __shared__ float cbuf[NF];                   // feature order c*9+tap
    __shared__ float p1[8][NMLP], pb[8][NMLP];
    __shared__ float h1[NMLP], h2[NMLP], hb[NMLP], lrs[NRANK];
    const int tid = threadIdx.x;
    const int lane = tid & 63, wv = tid >> 6;    // wv 0..15
    const int* lab = labels + b * NPIX;

    // ---- order-preserving compaction (4 iterations)
    int total = 0;
    #pragma unroll 1
    for (int base = 0; base < NPIX; base += 1024) {
        int n = base + tid;
        bool pred = (lab[n] == k);
        unsigned long long m = __ballot(pred);
        if (lane == 0) wcnt[wv] = __popcll(m);
        int pre = __popcll(m & ((1ull << lane) - 1ull));
        __syncthreads();
        int wbase = total;
        for (int i = 0; i < wv; ++i) wbase += wcnt[i];
        int nt = total;
        for (int i = 0; i < 16; ++i) nt += wcnt[i];
        if (pred) {
            int slot = wbase + pre;
            list[slot] = (unsigned short)n;
            slotmap[b * NPIX + n] = (unsigned short)slot;
        }
        total = nt;
        __syncthreads();
    }
    const int cnt = total;
    for (int i = tid; i < cnt; i += 1024) lists[bk * NPIX + i] = list[i];
    if (tid == 0) counts[bk] = cnt;
    __syncthreads();

    // ---- gather: wave wv handles pixels i = wv, wv+16, ...; lane = channel.
    // 9 independent 2B loads per pixel (one 128B segment per tap across wave).
    float s00 = 0.f, s01 = 0.f, s02 = 0.f,
          s10 = 0.f, s11 = 0.f, s12 = 0.f,
          s20 = 0.f, s21 = 0.f, s22 = 0.f;
    const unsigned short* xb = xcl + (size_t)b * (XH * XH * 64) + lane;
    #pragma unroll 1
    for (int i = wv; i < cnt; i += 16) {
        int n = list[i];
        const unsigned short* p0 = xb + (((n >> 6) * XH) + (n & 63)) * 64;
        s00 += bf2f(p0[0]);
        s01 += bf2f(p0[64]);
        s02 += bf2f(p0[128]);
        const unsigned short* prow1 = p0 + XH * 64;
        s10 += bf2f(prow1[0]);
        s11 += bf2f(prow1[64]);
        s12 += bf2f(prow1[128]);
        const unsigned short* prow2 = p0 + 2 * XH * 64;
        s20 += bf2f(prow2[0]);
        s21 += bf2f(prow2[64]);
        s22 += bf2f(prow2[128]);
    }
    {
        float* wrow = wsum + wv * 576 + lane;
        wrow[0 * 64] = s00; wrow[1 * 64] = s01; wrow[2 * 64] = s02;
        wrow[3 * 64] = s10; wrow[4 * 64] = s11; wrow[5 * 64] = s12;
        wrow[6 * 64] = s20; wrow[7 * 64] = s21; wrow[8 * 64] = s22;
    }
    __syncthreads();

    // ---- reduce 16 waves -> centers (feature order c*9+tap)
    const float inv = 1.f / ((float)cnt + 1e-6f);
    if (tid < NF) {
        int tap = tid >> 6, c = tid & 63;
        float s = 0.f;
        #pragma unroll
        for (int w = 0; w < 16; ++w) s += wsum[w * 576 + tap * 64 + c];
        cbuf[c * 9 + tap] = s * inv;
    }
    __syncthreads();

    // ---- fused MLPs (tid < 256 active; barriers block-wide)
    if (tid < 256) {
        const int j = tid & 31, ch = tid >> 5;       // 8 chunks x 72 feats
        float a1 = 0.f, a2 = 0.f;
        for (int i = 0; i < 72; ++i) {
            int f = ch * 72 + i;
            float cv = cbuf[f];
            a1 += cv * lw1[f * NMLP + j];
            a2 += cv * bw1[f * NMLP + j];
        }
        p1[ch][j] = a1; pb[ch][j] = a2;
    }
    __syncthreads();
    if (tid < NMLP) {
        float a = lb1[tid];
        for (int i = 0; i < 8; ++i) a += p1[i][tid];
        h1[tid] = fmaxf(a, 0.f);
    } else if (tid < 2 * NMLP) {
        int j = tid - NMLP;
        float a = bb1[j];
        for (int i = 0; i < 8; ++i) a += pb[i][j];
        hb[j] = fmaxf(a, 0.f);
    }
    __syncthreads();
    if (tid < NMLP) {
        float a = lb2[tid];
        for (int i = 0; i < NMLP; ++i) a += h1[i] * lw2[i * NMLP + tid];
        h2[tid] = fmaxf(a, 0.f);
    } else if (tid >= 64 && tid < 128) {
        int o = tid - 64;
        float a = bb2[o];
        for (int i = 0; i < NMLP; ++i) a += hb[i] * bw2[i * NOUT + o];
        biasrows[bk * NOUT + o] = a;
    }
    __syncthreads();
    if (tid < NRANK) {
        float a = lb3[tid];
        for (int i = 0; i < NMLP; ++i) a += h2[i] * lw3[i * NRANK + tid];
        lrs[tid] = a;
    }
    __syncthreads();

    // ---- fused W-expansion: wt[bk][ks][t][8], coalesced in and out.
    float l8[NRANK];
    #pragma unroll
    for (int r = 0; r < NRANK; ++r) l8[r] = lrs[r];
    unsigned short* wtg = wt + (size_t)bk * (18 * 2048);
    #pragma unroll 1
    for (int q = 0; q < 5; ++q) {
        int m = q * 1024 + tid;            // 0..4607 valid
        if (m < 4608) {
            int ks = m >> 8, t = m & 255;
            const unsigned short* src = basekF
                + ((size_t)(ks * 4 + (t >> 6)) * 8) * 512 + (t & 63) * 8;
            float w[8] = {0.f, 0.f, 0.f, 0.f, 0.f, 0.f, 0.f, 0.f};
            #pragma unroll
            for (int r = 0; r < NRANK; ++r) {
                s16x8 bv = *reinterpret_cast<const s16x8*>(src + r * 512);
                #pragma unroll
                for (int j = 0; j < 8; ++j)
                    w[j] += l8[r] * bf2f((unsigned short)bv[j]);
            }
            s16x8 f;
            #pragma unroll
            for (int j = 0; j < 8; ++j) f[j] = (short)f2bf(w[j]);
            *reinterpret_cast<s16x8*>(wtg + ks * 2048 + t * 8) = f;
        }
    }
}

// ---------------------------------------------------------------------------
// k_main (R9, unchanged): gathered GEMM. grid 1024 = 4 splits x 256 (b,k).
// B-fragments: 18 coalesced 1KB wave-loads from precomputed wt. Full unroll
// -> constant indices -> registers (R7 scratch-spill lesson).
// ---------------------------------------------------------------------------
extern "C" __global__ __launch_bounds__(256)
void k_main(const unsigned short* __restrict__ xcl, const unsigned short* __restrict__ lists,
            const int* __restrict__ counts, const unsigned short* __restrict__ wt,
            const float* __restrict__ biasrows, unsigned short* __restrict__ outc)
{
    const int blk = blockIdx.x;
    const int bk = blk & 255, split = blk >> 8;      // 0..3
    const int b = bk & 15, k = bk >> 4;
    const int tid = threadIdx.x;
    const int lane = tid & 63, wv = tid >> 6;
    const int quad = lane >> 4, l16 = lane & 15;
    const int cnt = counts[bk];
    int prefix = 0;
    for (int kk = 0; kk < k; ++kk) prefix += counts[kk * 16 + b];

    __shared__ __align__(16) unsigned short albuf[32 * 584];  // 36.5 KB
    __shared__ float biasl[NOUT];

    if (tid < NOUT) biasl[tid] = biasrows[bk * NOUT + tid];

    const int col = wv * 16 + l16;
    const unsigned short* wsrc = wt + (size_t)bk * (18 * 2048) + tid * 8;
    s16x8 bfr[18];
    #pragma unroll
    for (int ks = 0; ks < 18; ++ks)
        bfr[ks] = *reinterpret_cast<const s16x8*>(wsrc + ks * 2048);

    const unsigned short* xb = xcl + (size_t)b * (XH * XH * 64);
    const unsigned short* gl = lists + bk * NPIX;
    const int p = tid >> 3, part = tid & 7;
    const int ntile = (cnt + 31) >> 5;

    for (int t = split; t < ntile; t += 4) {
        int slot = (t << 5) + p;
        int n = (slot < cnt) ? (int)gl[slot] : 0;
        const unsigned short* xrow = xb + (((n >> 6) * XH) + (n & 63)) * 64 + part * 8;
        unsigned short* arow = albuf + p * 584 + part * 8;
        #pragma unroll
        for (int tap = 0; tap < 9; ++tap) {
            int dy = tap / 3, dx = tap - dy * 3;
            *reinterpret_cast<s16x8*>(arow + tap * 64) =
                *reinterpret_cast<const s16x8*>(xrow + (dy * XH + dx) * 64);
        }
        __syncthreads();

        f32x4 acc0 = {0.f, 0.f, 0.f, 0.f}, acc1 = {0.f, 0.f, 0.f, 0.f};
        const unsigned short* ar0 = albuf + l16 * 584 + quad * 8;
        const unsigned short* ar1 = ar0 + 16 * 584;
        #pragma unroll
        for (int ks = 0; ks < 18; ++ks) {
            s16x8 a0 = *reinterpret_cast<const s16x8*>(ar0 + ks * 32);
            s16x8 a1 = *reinterpret_cast<const s16x8*>(ar1 + ks * 32);
            acc0 = __builtin_amdgcn_mfma_f32_16x16x32_bf16(a0, bfr[ks], acc0, 0, 0, 0);
            acc1 = __builtin_amdgcn_mfma_f32_16x16x32_bf16(a1, bfr[ks], acc1, 0, 0, 0);
        }
        __syncthreads();

        float bb = biasl[col];
        unsigned short* ob = outc + ((size_t)b * NPIX + prefix) * 64;
        #pragma unroll
        for (int r = 0; r < 4; ++r) {
            int s0 = (t << 5) + quad * 4 + r;
            if (s0 < cnt) ob[(size_t)s0 * 64 + col] = f2bf(acc0[r] + bb);
            int s1 = s0 + 16;
            if (s1 < cnt) ob[(size_t)s1 * 64 + col] = f2bf(acc1[r] + bb);
        }
    }
}

// ---------------------------------------------------------------------------
// k_scatter: grid 1024 (4 blocks/CU — R11 TLP fix). block (b, chunk, q):
// o-range [q*16, q*16+16). 16B gathers, LDS transpose (rows padded to
// 20 u16), coalesced f32 stores.
// ---------------------------------------------------------------------------
extern "C" __global__ __launch_bounds__(256)
void k_scatter(const int* __restrict__ labels, const unsigned short* __restrict__ slotmap,
               const int* __restrict__ counts, const unsigned short* __restrict__ outc,
               float* __restrict__ out)
{
    const int blk = blockIdx.x;
    const int b = blk & 15, chunk = (blk >> 4) & 15, q = blk >> 8;
    const int tid = threadIdx.x;
    __shared__ int pref[KC];
    __shared__ int sptr[256];
    __shared__ unsigned short tt[256 * 20];     // 10 KB
    if (tid < KC) {
        int s = 0;
        for (int kk = 0; kk < tid; ++kk) s += counts[kk * 16 + b];
        pref[tid] = s;
    }
    __syncthreads();
    const int n0 = chunk * 256;
    {
        int n = n0 + tid;
        sptr[tid] = pref[labels[b * NPIX + n]] + (int)slotmap[b * NPIX + n];
    }
    __syncthreads();
    #pragma unroll
    for (int e0 = 0; e0 < 2; ++e0) {
        int e = e0 * 256 + tid;
        int pix = e >> 1, part = e & 1;
        s16x8 vv = *reinterpret_cast<const s16x8*>(
            outc + ((size_t)b * NPIX + sptr[pix]) * 64 + q * 16 + part * 8);
        s16x4 lo = {vv[0], vv[1], vv[2], vv[3]};
        s16x4 hi = {vv[4], vv[5], vv[6], vv[7]};
        *reinterpret_cast<s16x4*>(tt + pix * 20 + part * 8) = lo;
        *reinterpret_cast<s16x4*>(tt + pix * 20 + part * 8 + 4) = hi;
    }
    __syncthreads();
    float* ob = out + ((size_t)(b * NOUT + q * 16)) * NPIX + n0;
    #pragma unroll
    for (int oo = 0; oo < 16; ++oo)
        ob[(size_t)oo * NPIX + tid] = bf2f(tt[tid * 20 + oo]);
}

// ---------------------------------------------------------------------------
// Workspace layout — TOTAL 39,068,672 B:
//   lists    @ 0         : 2,097,152
//   counts   @ 2097152   : 1,024
//   biasrows @ 2098176   : 65,536
//   basekF   @ 2163712   : 589,824
//   slotmap  @ 2753536   : 131,072
//   xcl      @ 2884608   : 8,921,088
//   outc     @ 11805696  : 8,388,608
//   wt       @ 20194304  : 18,874,368
// ---------------------------------------------------------------------------
extern "C" void kernel_launch(void* const* d_in, const int* in_sizes, int n_in,
                              void* d_out, int out_size, void* d_ws, size_t ws_size,
                              hipStream_t stream)
{
    const float* x      = (const float*)d_in[0];
    const int*   labels = (const int*)d_in[1];
    const float* lw1    = (const float*)d_in[2];
    const float* lb1    = (const float*)d_in[3];
    const float* lw2    = (const float*)d_in[4];
    const float* lb2    = (const float*)d_in[5];
    const float* lw3    = (const float*)d_in[6];
    const float* lb3    = (const float*)d_in[7];
    const float* basek  = (const float*)d_in[8];
    const float* bw1    = (const float*)d_in[9];
    const float* bb1    = (const float*)d_in[10];
    const float* bw2    = (const float*)d_in[11];
    const float* bb2    = (const float*)d_in[12];
    float* out = (float*)d_out;

    char* ws = (char*)d_ws;
    unsigned short* lists   = (unsigned short*)(ws);
    int*            counts  = (int*)(ws + 2097152);
    float*          biasrows= (float*)(ws + 2098176);
    unsigned short* basekF  = (unsigned short*)(ws + 2163712);
    unsigned short* slotmap = (unsigned short*)(ws + 2753536);
    unsigned short* xcl     = (unsigned short*)(ws + 2884608);
    unsigned short* outc    = (unsigned short*)(ws + 11805696);
    unsigned short* wt      = (unsigned short*)(ws + 20194304);

    k_prep_all<<<XH * 16 + 72, 256, 0, stream>>>(x, basek, xcl, basekF);
    k_centers<<<256, 1024, 0, stream>>>(xcl, labels, lw1, lb1, lw2, lb2, lw3, lb3,
                                        bw1, bb1, bw2, bb2, basekF,
                                        lists, slotmap, counts, biasrows, wt);
    k_main<<<1024, 256, 0, stream>>>(xcl, lists, counts, wt, biasrows, outc);
    k_scatter<<<1024, 256, 0, stream>>>(labels, slotmap, counts, outc, out);
}

// Round 12
// 138.919 us; speedup vs baseline: 1.2451x; 1.0042x over previous
//
#include <hip/hip_runtime.h>
#include <stdint.h>
#include <stddef.h>

// Problem constants
#define NB   16
#define NC   64
#define NH   64
#define NW   64
#define KC   16
#define NOUT 64
#define NRANK 8
#define NMLP 32
#define NF   576      // C*3*3
#define NPIX 4096     // H*W
#define XH   66       // halo height/width for channel-last copy

typedef short s16x8 __attribute__((ext_vector_type(8)));
typedef short s16x4 __attribute__((ext_vector_type(4)));
typedef float f32x4 __attribute__((ext_vector_type(4)));

__device__ __forceinline__ unsigned short f2bf(float x) {
    union { float f; uint32_t u; } v; v.f = x;
    uint32_t r = v.u + 0x7FFFu + ((v.u >> 16) & 1u);   // RTNE
    return (unsigned short)(r >> 16);
}
__device__ __forceinline__ float bf2f(unsigned short u) {
    union { uint32_t u; float f; } v; v.u = ((uint32_t)u) << 16;
    return v.f;
}

// ---------------------------------------------------------------------------
// k_prep_all (unchanged): blocks [0,1056): xcl; [1056,1128): basekF.
// ---------------------------------------------------------------------------
extern "C" __global__ __launch_bounds__(256)
void k_prep_all(const float* __restrict__ x, const float* __restrict__ basek,
                unsigned short* __restrict__ xcl, unsigned short* __restrict__ basekF)
{
    __shared__ float tile[64 * 65];
    const int blk0 = blockIdx.x;
    const int tid = threadIdx.x;
    if (blk0 < XH * 16) {
        const int b = blk0 & 15, yy = blk0 >> 4;
        unsigned short* dst = xcl + ((size_t)(b * XH + yy) * XH) * 64;
        if (yy == 0 || yy == XH - 1) {
            for (int e = tid; e < XH * 64; e += 256) dst[e] = 0;
            return;
        }
        const int y = yy - 1;
        const float* src = x + (size_t)b * NC * (NH * NW) + y * NW;
        #pragma unroll
        for (int rr = 0; rr < 16; ++rr) {
            int c = rr * 4 + (tid >> 6);
            int xx = tid & 63;
            tile[c * 65 + xx] = src[(size_t)c * (NH * NW) + xx];
        }
        __syncthreads();
        for (int ee = tid; ee < 528; ee += 256) {
            int xx = ee >> 3;
            int c0 = (ee & 7) * 8;
            s16x8 v;
            #pragma unroll
            for (int j = 0; j < 8; ++j) {
                float f = (xx == 0 || xx == XH - 1) ? 0.f : tile[(c0 + j) * 65 + (xx - 1)];
                v[j] = (short)f2bf(f);
            }
            *reinterpret_cast<s16x8*>(dst + ee * 8) = v;
        }
    } else {
        const int blk = blk0 - XH * 16;    // ks*4 + wv
        const int ks = blk >> 2, wv = blk & 3;
        unsigned short outv[16];
        #pragma unroll
        for (int i = 0; i < 16; ++i) {
            int e = tid * 16 + i;          // e = r*512 + lane*8 + j
            int r = e >> 9;
            int lane = (e >> 3) & 63;
            int j = e & 7;
            int col = wv * 16 + (lane & 15);
            int fp = (lane >> 4) * 8 + ks * 32 + j;
            int tap = fp >> 6, c = fp & 63;
            outv[i] = f2bf(basek[((size_t)r * NF + c * 9 + tap) * NOUT + col]);
        }
        unsigned short* dst = basekF + (size_t)blk * 4096 + tid * 16;
        #pragma unroll
        for (int i = 0; i < 16; ++i) dst[i] = outv[i];
    }
}

// ---------------------------------------------------------------------------
// k_centers: 1024 threads (16 waves/CU). Compaction (4 ballot iters) ->
// gather (wave = pixel-slice, lane = channel; R12: unroll 2 for 2 pixel
// round-trips in flight — no register-array indexing, so partial unroll is
// spill-safe here unlike the R4-R6 bfr case) -> 16-wave LDS reduction ->
// MLPs -> W-expansion (R12: unroll 2). grid 256 (k*16+b).
// ---------------------------------------------------------------------------
extern "C" __global__ __launch_bounds__(1024)
void k_centers(const unsigned short* __restrict__ xcl, const int* __restrict__ labels,
               const float* __restrict__ lw1, const float* __restrict__ lb1,
               const float* __restrict__ lw2, const float* __restrict__ lb2,
               const float* __restrict__ lw3, const float* __restrict__ lb3,
               const float* __restrict__ bw1, const float* __restrict__ bb1,
               const float* __restrict__ bw2, const float* __restrict__ bb2,
               const unsigned short* __restrict__ basekF,
               unsigned short* __restrict__ lists, unsigned short* __restrict__ slotmap,
               int* __restrict__ counts, float* __restrict__ biasrows,
               unsigned short* __restrict__ wt)
{
    const int bk = blockIdx.x;
    const int b = bk & 15, k = bk >> 4;
    __shared__ unsigned short list[NPIX];        // 8 KB
    __shared__ int wcnt[16];
    __shared__ float wsum[16 * 9 * 64];          // 36.9 KB
    __shared__ float cbuf[NF];                   // feature order c*9+tap
    __shared__ float p1[8][NMLP], pb[8][NMLP];
    __shared__ float h1[NMLP], h2[NMLP], hb[NMLP], lrs[NRANK];
    const int tid = threadIdx.x;
    const int lane = tid & 63, wv = tid >> 6;    // wv 0..15
    const int* lab = labels + b * NPIX;

    // ---- order-preserving compaction (4 iterations)
    int total = 0;
    #pragma unroll 1
    for (int base = 0; base < NPIX; base += 1024) {
        int n = base + tid;
        bool pred = (lab[n] == k);
        unsigned long long m = __ballot(pred);
        if (lane == 0) wcnt[wv] = __popcll(m);
        int pre = __popcll(m & ((1ull << lane) - 1ull));
        __syncthreads();
        int wbase = total;
        for (int i = 0; i < wv; ++i) wbase += wcnt[i];
        int nt = total;
        for (int i = 0; i < 16; ++i) nt += wcnt[i];
        if (pred) {
            int slot = wbase + pre;
            list[slot] = (unsigned short)n;
            slotmap[b * NPIX + n] = (unsigned short)slot;
        }
        total = nt;
        __syncthreads();
    }
    const int cnt = total;
    for (int i = tid; i < cnt; i += 1024) lists[bk * NPIX + i] = list[i];
    if (tid == 0) counts[bk] = cnt;
    __syncthreads();

    // ---- gather: wave wv handles pixels i = wv, wv+16, ...; lane = channel.
    // 9 independent 2B loads per pixel; unroll 2 => 18 loads + 2 LDS list
    // reads in flight per chain step.
    float s00 = 0.f, s01 = 0.f, s02 = 0.f,
          s10 = 0.f, s11 = 0.f, s12 = 0.f,
          s20 = 0.f, s21 = 0.f, s22 = 0.f;
    const unsigned short* xb = xcl + (size_t)b * (XH * XH * 64) + lane;
    #pragma unroll 2
    for (int i = wv; i < cnt; i += 16) {
        int n = list[i];
        const unsigned short* p0 = xb + (((n >> 6) * XH) + (n & 63)) * 64;
        s00 += bf2f(p0[0]);
        s01 += bf2f(p0[64]);
        s02 += bf2f(p0[128]);
        const unsigned short* prow1 = p0 + XH * 64;
        s10 += bf2f(prow1[0]);
        s11 += bf2f(prow1[64]);
        s12 += bf2f(prow1[128]);
        const unsigned short* prow2 = p0 + 2 * XH * 64;
        s20 += bf2f(prow2[0]);
        s21 += bf2f(prow2[64]);
        s22 += bf2f(prow2[128]);
    }
    {
        float* wrow = wsum + wv * 576 + lane;
        wrow[0 * 64] = s00; wrow[1 * 64] = s01; wrow[2 * 64] = s02;
        wrow[3 * 64] = s10; wrow[4 * 64] = s11; wrow[5 * 64] = s12;
        wrow[6 * 64] = s20; wrow[7 * 64] = s21; wrow[8 * 64] = s22;
    }
    __syncthreads();

    // ---- reduce 16 waves -> centers (feature order c*9+tap)
    const float inv = 1.f / ((float)cnt + 1e-6f);
    if (tid < NF) {
        int tap = tid >> 6, c = tid & 63;
        float s = 0.f;
        #pragma unroll
        for (int w = 0; w < 16; ++w) s += wsum[w * 576 + tap * 64 + c];
        cbuf[c * 9 + tap] = s * inv;
    }
    __syncthreads();

    // ---- fused MLPs (tid < 256 active; barriers block-wide)
    if (tid < 256) {
        const int j = tid & 31, ch = tid >> 5;       // 8 chunks x 72 feats
        float a1 = 0.f, a2 = 0.f;
        for (int i = 0; i < 72; ++i) {
            int f = ch * 72 + i;
            float cv = cbuf[f];
            a1 += cv * lw1[f * NMLP + j];
            a2 += cv * bw1[f * NMLP + j];
        }
        p1[ch][j] = a1; pb[ch][j] = a2;
    }
    __syncthreads();
    if (tid < NMLP) {
        float a = lb1[tid];
        for (int i = 0; i < 8; ++i) a += p1[i][tid];
        h1[tid] = fmaxf(a, 0.f);
    } else if (tid < 2 * NMLP) {
        int j = tid - NMLP;
        float a = bb1[j];
        for (int i = 0; i < 8; ++i) a += pb[i][j];
        hb[j] = fmaxf(a, 0.f);
    }
    __syncthreads();
    if (tid < NMLP) {
        float a = lb2[tid];
        for (int i = 0; i < NMLP; ++i) a += h1[i] * lw2[i * NMLP + tid];
        h2[tid] = fmaxf(a, 0.f);
    } else if (tid >= 64 && tid < 128) {
        int o = tid - 64;
        float a = bb2[o];
        for (int i = 0; i < NMLP; ++i) a += hb[i] * bw2[i * NOUT + o];
        biasrows[bk * NOUT + o] = a;
    }
    __syncthreads();
    if (tid < NRANK) {
        float a = lb3[tid];
        for (int i = 0; i < NMLP; ++i) a += h2[i] * lw3[i * NRANK + tid];
        lrs[tid] = a;
    }
    __syncthreads();

    // ---- fused W-expansion: wt[bk][ks][t][8], coalesced in and out.
    // unroll 2: no cross-iteration register-array indexing -> spill-safe.
    float l8[NRANK];
    #pragma unroll
    for (int r = 0; r < NRANK; ++r) l8[r] = lrs[r];
    unsigned short* wtg = wt + (size_t)bk * (18 * 2048);
    #pragma unroll 2
    for (int q = 0; q < 5; ++q) {
        int m = q * 1024 + tid;            // 0..4607 valid
        if (m < 4608) {
            int ks = m >> 8, t = m & 255;
            const unsigned short* src = basekF
                + ((size_t)(ks * 4 + (t >> 6)) * 8) * 512 + (t & 63) * 8;
            float w[8] = {0.f, 0.f, 0.f, 0.f, 0.f, 0.f, 0.f, 0.f};
            #pragma unroll
            for (int r = 0; r < NRANK; ++r) {
                s16x8 bv = *reinterpret_cast<const s16x8*>(src + r * 512);
                #pragma unroll
                for (int j = 0; j < 8; ++j)
                    w[j] += l8[r] * bf2f((unsigned short)bv[j]);
            }
            s16x8 f;
            #pragma unroll
            for (int j = 0; j < 8; ++j) f[j] = (short)f2bf(w[j]);
            *reinterpret_cast<s16x8*>(wtg + ks * 2048 + t * 8) = f;
        }
    }
}

// ---------------------------------------------------------------------------
// k_main (unchanged): gathered GEMM. grid 1024 = 4 splits x 256 (b,k).
// B-fragments: 18 coalesced 1KB wave-loads from precomputed wt. Full unroll
// -> constant indices -> registers (R7 scratch-spill lesson).
// ---------------------------------------------------------------------------
extern "C" __global__ __launch_bounds__(256)
void k_main(const unsigned short* __restrict__ xcl, const unsigned short* __restrict__ lists,
            const int* __restrict__ counts, const unsigned short* __restrict__ wt,
            const float* __restrict__ biasrows, unsigned short* __restrict__ outc)
{
    const int blk = blockIdx.x;
    const int bk = blk & 255, split = blk >> 8;      // 0..3
    const int b = bk & 15, k = bk >> 4;
    const int tid = threadIdx.x;
    const int lane = tid & 63, wv = tid >> 6;
    const int quad = lane >> 4, l16 = lane & 15;
    const int cnt = counts[bk];
    int prefix = 0;
    for (int kk = 0; kk < k; ++kk) prefix += counts[kk * 16 + b];

    __shared__ __align__(16) unsigned short albuf[32 * 584];  // 36.5 KB
    __shared__ float biasl[NOUT];

    if (tid < NOUT) biasl[tid] = biasrows[bk * NOUT + tid];

    const int col = wv * 16 + l16;
    const unsigned short* wsrc = wt + (size_t)bk * (18 * 2048) + tid * 8;
    s16x8 bfr[18];
    #pragma unroll
    for (int ks = 0; ks < 18; ++ks)
        bfr[ks] = *reinterpret_cast<const s16x8*>(wsrc + ks * 2048);

    const unsigned short* xb = xcl + (size_t)b * (XH * XH * 64);
    const unsigned short* gl = lists + bk * NPIX;
    const int p = tid >> 3, part = tid & 7;
    const int ntile = (cnt + 31) >> 5;

    for (int t = split; t < ntile; t += 4) {
        int slot = (t << 5) + p;
        int n = (slot < cnt) ? (int)gl[slot] : 0;
        const unsigned short* xrow = xb + (((n >> 6) * XH) + (n & 63)) * 64 + part * 8;
        unsigned short* arow = albuf + p * 584 + part * 8;
        #pragma unroll
        for (int tap = 0; tap < 9; ++tap) {
            int dy = tap / 3, dx = tap - dy * 3;
            *reinterpret_cast<s16x8*>(arow + tap * 64) =
                *reinterpret_cast<const s16x8*>(xrow + (dy * XH + dx) * 64);
        }
        __syncthreads();

        f32x4 acc0 = {0.f, 0.f, 0.f, 0.f}, acc1 = {0.f, 0.f, 0.f, 0.f};
        const unsigned short* ar0 = albuf + l16 * 584 + quad * 8;
        const unsigned short* ar1 = ar0 + 16 * 584;
        #pragma unroll
        for (int ks = 0; ks < 18; ++ks) {
            s16x8 a0 = *reinterpret_cast<const s16x8*>(ar0 + ks * 32);
            s16x8 a1 = *reinterpret_cast<const s16x8*>(ar1 + ks * 32);
            acc0 = __builtin_amdgcn_mfma_f32_16x16x32_bf16(a0, bfr[ks], acc0, 0, 0, 0);
            acc1 = __builtin_amdgcn_mfma_f32_16x16x32_bf16(a1, bfr[ks], acc1, 0, 0, 0);
        }
        __syncthreads();

        float bb = biasl[col];
        unsigned short* ob = outc + ((size_t)b * NPIX + prefix) * 64;
        #pragma unroll
        for (int r = 0; r < 4; ++r) {
            int s0 = (t << 5) + quad * 4 + r;
            if (s0 < cnt) ob[(size_t)s0 * 64 + col] = f2bf(acc0[r] + bb);
            int s1 = s0 + 16;
            if (s1 < cnt) ob[(size_t)s1 * 64 + col] = f2bf(acc1[r] + bb);
        }
    }
}

// ---------------------------------------------------------------------------
// k_scatter (unchanged): grid 1024 (4 blocks/CU). block (b, chunk, q):
// o-range [q*16, q*16+16). 16B gathers, LDS transpose (rows padded to
// 20 u16), coalesced f32 stores.
// ---------------------------------------------------------------------------
extern "C" __global__ __launch_bounds__(256)
void k_scatter(const int* __restrict__ labels, const unsigned short* __restrict__ slotmap,
               const int* __restrict__ counts, const unsigned short* __restrict__ outc,
               float* __restrict__ out)
{
    const int blk = blockIdx.x;
    const int b = blk & 15, chunk = (blk >> 4) & 15, q = blk >> 8;
    const int tid = threadIdx.x;
    __shared__ int pref[KC];
    __shared__ int sptr[256];
    __shared__ unsigned short tt[256 * 20];     // 10 KB
    if (tid < KC) {
        int s = 0;
        for (int kk = 0; kk < tid; ++kk) s += counts[kk * 16 + b];
        pref[tid] = s;
    }
    __syncthreads();
    const int n0 = chunk * 256;
    {
        int n = n0 + tid;
        sptr[tid] = pref[labels[b * NPIX + n]] + (int)slotmap[b * NPIX + n];
    }
    __syncthreads();
    #pragma unroll
    for (int e0 = 0; e0 < 2; ++e0) {
        int e = e0 * 256 + tid;
        int pix = e >> 1, part = e & 1;
        s16x8 vv = *reinterpret_cast<const s16x8*>(
            outc + ((size_t)b * NPIX + sptr[pix]) * 64 + q * 16 + part * 8);
        s16x4 lo = {vv[0], vv[1], vv[2], vv[3]};
        s16x4 hi = {vv[4], vv[5], vv[6], vv[7]};
        *reinterpret_cast<s16x4*>(tt + pix * 20 + part * 8) = lo;
        *reinterpret_cast<s16x4*>(tt + pix * 20 + part * 8 + 4) = hi;
    }
    __syncthreads();
    float* ob = out + ((size_t)(b * NOUT + q * 16)) * NPIX + n0;
    #pragma unroll
    for (int oo = 0; oo < 16; ++oo)
        ob[(size_t)oo * NPIX + tid] = bf2f(tt[tid * 20 + oo]);
}

// ---------------------------------------------------------------------------
// Workspace layout — TOTAL 39,068,672 B:
//   lists    @ 0         : 2,097,152
//   counts   @ 2097152   : 1,024
//   biasrows @ 2098176   : 65,536
//   basekF   @ 2163712   : 589,824
//   slotmap  @ 2753536   : 131,072
//   xcl      @ 2884608   : 8,921,088
//   outc     @ 11805696  : 8,388,608
//   wt       @ 20194304  : 18,874,368
// ---------------------------------------------------------------------------
extern "C" void kernel_launch(void* const* d_in, const int* in_sizes, int n_in,
                              void* d_out, int out_size, void* d_ws, size_t ws_size,
                              hipStream_t stream)
{
    const float* x      = (const float*)d_in[0];
    const int*   labels = (const int*)d_in[1];
    const float* lw1    = (const float*)d_in[2];
    const float* lb1    = (const float*)d_in[3];
    const float* lw2    = (const float*)d_in[4];
    const float* lb2    = (const float*)d_in[5];
    const float* lw3    = (const float*)d_in[6];
    const float* lb3    = (const float*)d_in[7];
    const float* basek  = (const float*)d_in[8];
    const float* bw1    = (const float*)d_in[9];
    const float* bb1    = (const float*)d_in[10];
    const float* bw2    = (const float*)d_in[11];
    const float* bb2    = (const float*)d_in[12];
    float* out = (float*)d_out;

    char* ws = (char*)d_ws;
    unsigned short* lists   = (unsigned short*)(ws);
    int*            counts  = (int*)(ws + 2097152);
    float*          biasrows= (float*)(ws + 2098176);
    unsigned short* basekF  = (unsigned short*)(ws + 2163712);
    unsigned short* slotmap = (unsigned short*)(ws + 2753536);
    unsigned short* xcl     = (unsigned short*)(ws + 2884608);
    unsigned short* outc    = (unsigned short*)(ws + 11805696);
    unsigned short* wt      = (unsigned short*)(ws + 20194304);

    k_prep_all<<<XH * 16 + 72, 256, 0, stream>>>(x, basek, xcl, basekF);
    k_centers<<<256, 1024, 0, stream>>>(xcl, labels, lw1, lb1, lw2, lb2, lw3, lb3,
                                        bw1, bb1, bw2, bb2, basekF,
                                        lists, slotmap, counts, biasrows, wt);
    k_main<<<1024, 256, 0, stream>>>(xcl, lists, counts, wt, biasrows, outc);
    k_scatter<<<1024, 256, 0, stream>>>(labels, slotmap, counts, outc, out);
}